// Round 11
// baseline (388.992 us; speedup 1.0000x reference)
//
#include <hip/hip_runtime.h>

typedef __bf16 bf16;
typedef bf16 bf16x8 __attribute__((ext_vector_type(8)));
typedef float f32x4 __attribute__((ext_vector_type(4)));
typedef float f32x16 __attribute__((ext_vector_type(16)));

#define B_   4
#define N_   2048
#define DIM_ 1024
#define H_   16
#define DH_  64
#define M_   (B_ * N_)   // 8192

// log2(e) * (1/sqrt(64))
#define CEXP 0.18033688f

#define GLOBAL_CP(g) (const __attribute__((address_space(1))) void*)(g)
#define LDS_CP(l)    (__attribute__((address_space(3))) void*)(l)

// ---------------------------------------------------------------------------
// fused fp32 -> bf16 conversion for x | wqkv | wproj (contiguous dest in ws).
// ---------------------------------------------------------------------------
__global__ __launch_bounds__(256) void cvt_all(
    const float* __restrict__ x, const float* __restrict__ wq,
    const float* __restrict__ wp, bf16* __restrict__ o,
    int nx4, int nwq4, int nwp4)
{
    const int i = blockIdx.x * blockDim.x + threadIdx.x;
    const float* src; int si;
    if (i < nx4)                { src = x;  si = i; }
    else if (i < nx4 + nwq4)    { src = wq; si = i - nx4; }
    else                        { src = wp; si = i - nx4 - nwq4; }
    const float4 v = ((const float4*)src)[si];
    union { bf16 h[4]; uint2 u; } r;
    r.h[0] = (bf16)v.x; r.h[1] = (bf16)v.y;
    r.h[2] = (bf16)v.z; r.h[3] = (bf16)v.w;
    ((uint2*)o)[i] = r.u;
}

// ---------------------------------------------------------------------------
// GEMM (unchanged from R10): m97 global_load_lds staging + XOR source swizzle.
// mode 0: fp32 C row-major; mode 1: scatter q/k [bh][n][d] (Q pre-scaled) +
// V transposed [bh][d][n].
// ---------------------------------------------------------------------------
__global__ __launch_bounds__(256) void gemm_bt(
    const bf16* __restrict__ A, const bf16* __restrict__ Bm,
    int Ndim, int K, int mode,
    float* __restrict__ outf,
    bf16* __restrict__ qb, bf16* __restrict__ kbv, bf16* __restrict__ vbT)
{
    __shared__ bf16 As[128 * 32];
    __shared__ bf16 Bs[128 * 32];

    const int tid  = threadIdx.x;
    const int wave = tid >> 6;
    const int lane = tid & 63;
    const int quad = lane >> 4;
    const int lr   = lane & 15;
    const int wr   = wave >> 1, wc = wave & 1;
    const int m0 = blockIdx.y * 128;
    const int n0 = blockIdx.x * 128;

    f32x4 acc[4][4];
#pragma unroll
    for (int i = 0; i < 4; i++)
#pragma unroll
        for (int j = 0; j < 4; j++) acc[i][j] = f32x4{0.f, 0.f, 0.f, 0.f};

    const int srow = lane >> 2;
    const int scol = ((lane & 3) ^ ((srow >> 1) & 3)) * 8;

    for (int k0 = 0; k0 < K; k0 += 32) {
        __syncthreads();
#pragma unroll
        for (int j = 0; j < 2; j++) {
            const int rbase = j * 64 + wave * 16;
            __builtin_amdgcn_global_load_lds(
                GLOBAL_CP(A + (size_t)(m0 + rbase + srow) * K + k0 + scol),
                LDS_CP(&As[rbase * 32 + lane * 8]), 16, 0, 0);
            __builtin_amdgcn_global_load_lds(
                GLOBAL_CP(Bm + (size_t)(n0 + rbase + srow) * K + k0 + scol),
                LDS_CP(&Bs[rbase * 32 + lane * 8]), 16, 0, 0);
        }
        __syncthreads();

        bf16x8 af[4], bfr[4];
#pragma unroll
        for (int i = 0; i < 4; i++) {
            const int R = wr * 64 + i * 16 + lr;
            af[i] = *(const bf16x8*)(&As[R * 32 + ((quad ^ ((R >> 1) & 3)) << 3)]);
        }
#pragma unroll
        for (int j = 0; j < 4; j++) {
            const int R = wc * 64 + j * 16 + lr;
            bfr[j] = *(const bf16x8*)(&Bs[R * 32 + ((quad ^ ((R >> 1) & 3)) << 3)]);
        }
#pragma unroll
        for (int i = 0; i < 4; i++)
#pragma unroll
            for (int j = 0; j < 4; j++)
                acc[i][j] = __builtin_amdgcn_mfma_f32_16x16x32_bf16(
                    af[i], bfr[j], acc[i][j], 0, 0, 0);
    }

#pragma unroll
    for (int i = 0; i < 4; i++) {
        const int mbase = m0 + wr * 64 + i * 16 + quad * 4;
#pragma unroll
        for (int j = 0; j < 4; j++) {
            const int n = n0 + wc * 64 + j * 16 + lr;
            if (mode == 0) {
#pragma unroll
                for (int r = 0; r < 4; r++)
                    outf[(size_t)(mbase + r) * Ndim + n] = acc[i][j][r];
            } else {
                const int which = n >> 10;
                const int h = (n >> 6) & 15;
                const int d = n & 63;
                const int b  = mbase >> 11;
                const int t0 = mbase & 2047;
                if (which == 2) {
                    union { uint2 u; bf16 hh[4]; } p;
#pragma unroll
                    for (int r = 0; r < 4; r++) p.hh[r] = (bf16)acc[i][j][r];
                    *(uint2*)(&vbT[(((size_t)(b * 16 + h)) * 64 + d) * 2048 + t0]) = p.u;
                } else {
                    bf16* dst = (which == 0) ? qb : kbv;
                    const float sc = (which == 0) ? CEXP : 1.0f;
#pragma unroll
                    for (int r = 0; r < 4; r++)
                        dst[(((size_t)(b * 16 + h)) * 2048 + t0 + r) * 64 + d] =
                            (bf16)(acc[i][j][r] * sc);
                }
            }
        }
    }
}

// ---------------------------------------------------------------------------
// Flash attention v8: 32x32x16 MFMA. 1024 blocks, 128 q/block, wave = 32 q.
// S^T = K Q^T per 32-key block -> exp2 -> half-wave register exchange
// (shfl_xor 32) builds P A-frags -> PV. NO P LDS round-trip, no barrier C.
// LDS: Ks stride 66, Vs stride 130 (odd-dword => conflict-free 32-lane reads).
// 32x32x16 layouts: A[m=lane&31][k=(lane>>5)*8+j], B[n=lane&31][k=same];
// C/D: col=lane&31, row=(reg&3)+8*(reg>>2)+4*(lane>>5)  [m74/m101].
// ---------------------------------------------------------------------------
#define KS_S 66     // Ks stride (elems), 33 dwords (odd)
#define VS_S 130    // Vs stride (elems), 65 dwords (odd)

__global__ __launch_bounds__(256, 3) void attn_kernel(
    const bf16* __restrict__ qb, const bf16* __restrict__ kb,
    const bf16* __restrict__ vbT, bf16* __restrict__ ao)
{
    __shared__ bf16 Ks[128 * KS_S];   // 16896 B  [key][d]
    __shared__ bf16 Vs[64 * VS_S];    // 16640 B  [d][key]

    const int tid  = threadIdx.x;
    const int wave = tid >> 6;
    const int lane = tid & 63;
    const int l31  = lane & 31;
    const int hh   = lane >> 5;       // half-wave index

    // XCD swizzle: one head's 16 q-tiles on one XCD
    const int bid = blockIdx.x;
    const int qt  = (bid >> 3) & 15;
    const int bh  = ((bid >> 7) << 3) | (bid & 7);

    const bf16* Q  = qb  + (size_t)bh * N_ * DH_;
    const bf16* Kp = kb  + (size_t)bh * N_ * DH_;
    const bf16* Vp = vbT + (size_t)bh * DH_ * N_;   // [d][n]

    // Q B-frags: B[q=l31][d = ks*16 + hh*8 + j], loaded once from global
    bf16x8 qf[4];
#pragma unroll
    for (int ks = 0; ks < 4; ks++)
        qf[ks] = *(const bf16x8*)(Q + (size_t)(qt * 128 + wave * 32 + l31) * DH_
                                    + ks * 16 + hh * 8);

    const int krow = tid >> 1;          // 0..127 (key)
    const int khf  = tid & 1;           // d half
    const int vrow = tid >> 4;          // 0..15 (d), +16 per pass
    const int vchk = tid & 15;          // 16B key-chunk

    // prefetch tile 0
    uint4 kr[4], vr[4];
    {
        const uint4* kg = (const uint4*)(Kp + (size_t)krow * DH_ + khf * 32);
#pragma unroll
        for (int c = 0; c < 4; c++) kr[c] = kg[c];
#pragma unroll
        for (int c = 0; c < 4; c++)
            vr[c] = *(const uint4*)(Vp + (size_t)(vrow + 16 * c) * N_ + vchk * 8);
    }

    float lrow = 0.f;
    f32x16 oacc[2];
#pragma unroll
    for (int d = 0; d < 2; d++)
#pragma unroll
        for (int r = 0; r < 16; r++) oacc[d][r] = 0.f;

    for (int t = 0; t < N_ / 128; t++) {
        __syncthreads();   // A: prev-iter Ks/Vs readers done
#pragma unroll
        for (int c = 0; c < 4; c++)
            *(uint4*)(&Ks[krow * KS_S + khf * 32 + c * 8]) = kr[c];
#pragma unroll
        for (int c = 0; c < 4; c++)
            *(uint4*)(&Vs[(vrow + 16 * c) * VS_S + vchk * 8]) = vr[c];
        __syncthreads();   // B: staging visible

        // prefetch t+1 (in flight across the whole compute phase)
        if (t < N_ / 128 - 1) {
            const uint4* kg = (const uint4*)(Kp + (size_t)((t + 1) * 128 + krow) * DH_ + khf * 32);
#pragma unroll
            for (int c = 0; c < 4; c++) kr[c] = kg[c];
#pragma unroll
            for (int c = 0; c < 4; c++)
                vr[c] = *(const uint4*)(Vp + (size_t)(vrow + 16 * c) * N_
                                           + (t + 1) * 128 + vchk * 8);
        }

        float ssum = 0.f;
#pragma unroll
        for (int kbk = 0; kbk < 4; kbk++) {      // 32-key blocks
            // S^T = K Q^T : D[key][q], key-rows kbk*32..+31
            f32x16 e;
#pragma unroll
            for (int r = 0; r < 16; r++) e[r] = 0.f;
#pragma unroll
            for (int ks = 0; ks < 4; ks++) {
                bf16x8 ak = *(const bf16x8*)(&Ks[(kbk * 32 + l31) * KS_S
                                                 + ks * 16 + hh * 8]);
                e = __builtin_amdgcn_mfma_f32_32x32x16_bf16(ak, qf[ks], e, 0, 0, 0);
            }

            // softmax exponentials (Q pre-scaled by CEXP -> plain exp2)
#pragma unroll
            for (int r = 0; r < 16; r++) {
                e[r] = exp2f(e[r]);
                ssum += e[r];
            }

            // half-wave exchange: build P A-frags (keys kw*16 + hh*8 + j)
            float t1[4], t2[4];
#pragma unroll
            for (int j = 0; j < 4; j++) {
                const float s1 = hh ? e[j]     : e[4 + j];
                const float s2 = hh ? e[8 + j] : e[12 + j];
                t1[j] = __shfl_xor(s1, 32);
                t2[j] = __shfl_xor(s2, 32);
            }
            bf16x8 p0, p1;
#pragma unroll
            for (int j = 0; j < 4; j++) {
                p0[j]     = (bf16)(hh ? t1[j]      : e[j]);
                p0[4 + j] = (bf16)(hh ? e[4 + j]   : t1[j]);
                p1[j]     = (bf16)(hh ? t2[j]      : e[8 + j]);
                p1[4 + j] = (bf16)(hh ? e[12 + j]  : t2[j]);
            }

            // O += P V : D[q][d], B = V^T[d=l31][key]
#pragma unroll
            for (int dblk = 0; dblk < 2; dblk++) {
                bf16x8 bv0 = *(const bf16x8*)(&Vs[(dblk * 32 + l31) * VS_S
                                                  + kbk * 32 + hh * 8]);
                bf16x8 bv1 = *(const bf16x8*)(&Vs[(dblk * 32 + l31) * VS_S
                                                  + kbk * 32 + 16 + hh * 8]);
                oacc[dblk] = __builtin_amdgcn_mfma_f32_32x32x16_bf16(p0, bv0, oacc[dblk], 0, 0, 0);
                oacc[dblk] = __builtin_amdgcn_mfma_f32_32x32x16_bf16(p1, bv1, oacc[dblk], 0, 0, 0);
            }
        }
        ssum += __shfl_xor(ssum, 32);   // combine key-halves (same q = l31)
        lrow += ssum;
    }

    // epilogue: O row q=(r&3)+8*(r>>2)+4*hh, col d=dblk*32+l31
    const int head = bh & 15;
    const int b    = bh >> 4;
    const float linv = 1.0f / lrow;     // valid at lane with l31 == q
#pragma unroll
    for (int r = 0; r < 16; r++) {
        const int qr  = (r & 3) + 8 * (r >> 2) + 4 * hh;
        const float inv = __shfl(linv, qr);     // lane qr holds q=qr
        const int qrow = qt * 128 + wave * 32 + qr;
#pragma unroll
        for (int dblk = 0; dblk < 2; dblk++)
            ao[((size_t)(b * 2048 + qrow)) * 1024 + head * 64 + dblk * 32 + l31] =
                (bf16)(oacc[dblk][r] * inv);
    }
}

// ---------------------------------------------------------------------------
extern "C" void kernel_launch(void* const* d_in, const int* in_sizes, int n_in,
                              void* d_out, int out_size, void* d_ws, size_t ws_size,
                              hipStream_t stream)
{
    const float* x     = (const float*)d_in[0];   // [8192 x 1024] fp32
    const float* wqkv  = (const float*)d_in[1];   // [3072 x 1024] fp32
    const float* wproj = (const float*)d_in[2];   // [1024 x 1024] fp32
    float* out = (float*)d_out;                   // [8192 x 1024] fp32

    const size_t nx  = (size_t)M_ * DIM_;
    const size_t nwq = (size_t)3 * DIM_ * DIM_;
    const size_t nwp = (size_t)DIM_ * DIM_;
    const size_t seg = (size_t)B_ * H_ * N_ * DH_;

    bf16* xb     = (bf16*)d_ws;        // dead after QKV gemm; ao overlays it
    bf16* wqkvb  = xb + nx;            // contiguous with xb (cvt_all dest)
    bf16* wprojb = wqkvb + nwq;
    bf16* qb     = wprojb + nwp;
    bf16* kb     = qb + seg;
    bf16* vbT    = kb + seg;           // [bh][d][n]
    bf16* ao     = xb;

    const int nx4  = (int)(nx / 4), nwq4 = (int)(nwq / 4), nwp4 = (int)(nwp / 4);
    cvt_all<<<(nx4 + nwq4 + nwp4) / 256, 256, 0, stream>>>(
        x, wqkv, wproj, xb, nx4, nwq4, nwp4);

    gemm_bt<<<dim3(24, 64), 256, 0, stream>>>(xb, wqkvb, 3 * DIM_, DIM_, 1,
                                              nullptr, qb, kb, vbT);
    attn_kernel<<<dim3(1024), 256, 0, stream>>>(qb, kb, vbT, ao);
    gemm_bt<<<dim3(8, 64), 256, 0, stream>>>(ao, wprojb, DIM_, DIM_, 0,
                                             out, nullptr, nullptr, nullptr);
}

// Round 12
// 311.648 us; speedup vs baseline: 1.2482x; 1.2482x over previous
//
#include <hip/hip_runtime.h>

typedef __bf16 bf16;
typedef bf16 bf16x8 __attribute__((ext_vector_type(8)));
typedef float f32x4 __attribute__((ext_vector_type(4)));
typedef float f32x16 __attribute__((ext_vector_type(16)));

#define B_   4
#define N_   2048
#define DIM_ 1024
#define H_   16
#define DH_  64
#define M_   (B_ * N_)   // 8192

// log2(e) * (1/sqrt(64))
#define CEXP 0.18033688f

#define GLOBAL_CP(g) (const __attribute__((address_space(1))) void*)(g)
#define LDS_CP(l)    (__attribute__((address_space(3))) void*)(l)

// ---------------------------------------------------------------------------
// fused fp32 -> bf16 conversion for x | wqkv | wproj (contiguous dest in ws).
// ---------------------------------------------------------------------------
__global__ __launch_bounds__(256) void cvt_all(
    const float* __restrict__ x, const float* __restrict__ wq,
    const float* __restrict__ wp, bf16* __restrict__ o,
    int nx4, int nwq4, int nwp4)
{
    const int i = blockIdx.x * blockDim.x + threadIdx.x;
    const float* src; int si;
    if (i < nx4)                { src = x;  si = i; }
    else if (i < nx4 + nwq4)    { src = wq; si = i - nx4; }
    else                        { src = wp; si = i - nx4 - nwq4; }
    const float4 v = ((const float4*)src)[si];
    union { bf16 h[4]; uint2 u; } r;
    r.h[0] = (bf16)v.x; r.h[1] = (bf16)v.y;
    r.h[2] = (bf16)v.z; r.h[3] = (bf16)v.w;
    ((uint2*)o)[i] = r.u;
}

// ---------------------------------------------------------------------------
// GEMM (unchanged from R10): m97 global_load_lds staging + XOR source swizzle.
// mode 0: fp32 C row-major; mode 1: scatter q/k [bh][n][d] (Q pre-scaled) +
// V transposed [bh][d][n].
// ---------------------------------------------------------------------------
__global__ __launch_bounds__(256) void gemm_bt(
    const bf16* __restrict__ A, const bf16* __restrict__ Bm,
    int Ndim, int K, int mode,
    float* __restrict__ outf,
    bf16* __restrict__ qb, bf16* __restrict__ kbv, bf16* __restrict__ vbT)
{
    __shared__ bf16 As[128 * 32];
    __shared__ bf16 Bs[128 * 32];

    const int tid  = threadIdx.x;
    const int wave = tid >> 6;
    const int lane = tid & 63;
    const int quad = lane >> 4;
    const int lr   = lane & 15;
    const int wr   = wave >> 1, wc = wave & 1;
    const int m0 = blockIdx.y * 128;
    const int n0 = blockIdx.x * 128;

    f32x4 acc[4][4];
#pragma unroll
    for (int i = 0; i < 4; i++)
#pragma unroll
        for (int j = 0; j < 4; j++) acc[i][j] = f32x4{0.f, 0.f, 0.f, 0.f};

    const int srow = lane >> 2;
    const int scol = ((lane & 3) ^ ((srow >> 1) & 3)) * 8;

    for (int k0 = 0; k0 < K; k0 += 32) {
        __syncthreads();
#pragma unroll
        for (int j = 0; j < 2; j++) {
            const int rbase = j * 64 + wave * 16;
            __builtin_amdgcn_global_load_lds(
                GLOBAL_CP(A + (size_t)(m0 + rbase + srow) * K + k0 + scol),
                LDS_CP(&As[rbase * 32 + lane * 8]), 16, 0, 0);
            __builtin_amdgcn_global_load_lds(
                GLOBAL_CP(Bm + (size_t)(n0 + rbase + srow) * K + k0 + scol),
                LDS_CP(&Bs[rbase * 32 + lane * 8]), 16, 0, 0);
        }
        __syncthreads();

        bf16x8 af[4], bfr[4];
#pragma unroll
        for (int i = 0; i < 4; i++) {
            const int R = wr * 64 + i * 16 + lr;
            af[i] = *(const bf16x8*)(&As[R * 32 + ((quad ^ ((R >> 1) & 3)) << 3)]);
        }
#pragma unroll
        for (int j = 0; j < 4; j++) {
            const int R = wc * 64 + j * 16 + lr;
            bfr[j] = *(const bf16x8*)(&Bs[R * 32 + ((quad ^ ((R >> 1) & 3)) << 3)]);
        }
#pragma unroll
        for (int i = 0; i < 4; i++)
#pragma unroll
            for (int j = 0; j < 4; j++)
                acc[i][j] = __builtin_amdgcn_mfma_f32_16x16x32_bf16(
                    af[i], bfr[j], acc[i][j], 0, 0, 0);
    }

#pragma unroll
    for (int i = 0; i < 4; i++) {
        const int mbase = m0 + wr * 64 + i * 16 + quad * 4;
#pragma unroll
        for (int j = 0; j < 4; j++) {
            const int n = n0 + wc * 64 + j * 16 + lr;
            if (mode == 0) {
#pragma unroll
                for (int r = 0; r < 4; r++)
                    outf[(size_t)(mbase + r) * Ndim + n] = acc[i][j][r];
            } else {
                const int which = n >> 10;
                const int h = (n >> 6) & 15;
                const int d = n & 63;
                const int b  = mbase >> 11;
                const int t0 = mbase & 2047;
                if (which == 2) {
                    union { uint2 u; bf16 hh[4]; } p;
#pragma unroll
                    for (int r = 0; r < 4; r++) p.hh[r] = (bf16)acc[i][j][r];
                    *(uint2*)(&vbT[(((size_t)(b * 16 + h)) * 64 + d) * 2048 + t0]) = p.u;
                } else {
                    bf16* dst = (which == 0) ? qb : kbv;
                    const float sc = (which == 0) ? CEXP : 1.0f;
#pragma unroll
                    for (int r = 0; r < 4; r++)
                        dst[(((size_t)(b * 16 + h)) * 2048 + t0 + r) * 64 + d] =
                            (bf16)(acc[i][j][r] * sc);
                }
            }
        }
    }
}

// ---------------------------------------------------------------------------
// Flash attention v9: v8's 32x32x16 structure with K/V staged by
// global_load_lds DMA (width 16, XOR source-swizzled chunks) instead of
// register prefetch + ds_write. Frees 32 VGPRs (R11's spill) and all staging
// VALU. Unpadded strides (DMA requires lane-linear dest); swizzle keeps
// reads at 4-way (K) / 2-way (V) — cheap per m136.
// Ks[key][64]: slot s holds global chunk s^(row&7).
// Vs[d][128]:  slot s holds global chunk s^(row&15).
// ---------------------------------------------------------------------------
__global__ __launch_bounds__(256, 3) void attn_kernel(
    const bf16* __restrict__ qb, const bf16* __restrict__ kb,
    const bf16* __restrict__ vbT, bf16* __restrict__ ao)
{
    __shared__ bf16 Ks[128 * 64];   // 16384 B  [key][d], chunk-swizzled
    __shared__ bf16 Vs[64 * 128];   // 16384 B  [d][key], chunk-swizzled

    const int tid  = threadIdx.x;
    const int wave = tid >> 6;
    const int lane = tid & 63;
    const int l31  = lane & 31;
    const int hh   = lane >> 5;       // half-wave index

    // XCD swizzle: one head's 16 q-tiles on one XCD
    const int bid = blockIdx.x;
    const int qt  = (bid >> 3) & 15;
    const int bh  = ((bid >> 7) << 3) | (bid & 7);

    const bf16* Q  = qb  + (size_t)bh * N_ * DH_;
    const bf16* Kp = kb  + (size_t)bh * N_ * DH_;
    const bf16* Vp = vbT + (size_t)bh * DH_ * N_;   // [d][n]

    // Q B-frags: B[q=l31][d = ks*16 + hh*8 + j], loaded once from global
    bf16x8 qf[4];
#pragma unroll
    for (int ks = 0; ks < 4; ks++)
        qf[ks] = *(const bf16x8*)(Q + (size_t)(qt * 128 + wave * 32 + l31) * DH_
                                    + ks * 16 + hh * 8);

    // K staging map (per wave-issue c of 4): row = (wave*4+c)*8 + (lane>>3),
    // source chunk = (lane&7) ^ ((lane>>3)&7); dest lane-linear.
    const int krow0 = (lane >> 3);                       // + ii*8
    const int kscol = ((lane & 7) ^ ((lane >> 3) & 7)) * 8;
    // V staging map: row = (wave*4+c)*4 + (lane>>4), src chunk = (lane&15)^(row&15)
    const int vrow0 = (lane >> 4);                       // + ii*4

    float lrow = 0.f;
    f32x16 oacc[2];
#pragma unroll
    for (int d = 0; d < 2; d++)
#pragma unroll
        for (int r = 0; r < 16; r++) oacc[d][r] = 0.f;

    for (int t = 0; t < N_ / 128; t++) {
        __syncthreads();   // A: prev-iter Ks/Vs readers done
        // DMA-stage K tile (16 KB) and V tile (16 KB)
#pragma unroll
        for (int c = 0; c < 4; c++) {
            const int ii = wave * 4 + c;
            const int krow = ii * 8 + krow0;
            __builtin_amdgcn_global_load_lds(
                GLOBAL_CP(Kp + (size_t)(t * 128 + krow) * DH_ + kscol),
                LDS_CP(&Ks[ii * 512 + lane * 8]), 16, 0, 0);
            const int vrow = ii * 4 + vrow0;
            const int vscol = ((lane & 15) ^ (vrow & 15)) * 8;
            __builtin_amdgcn_global_load_lds(
                GLOBAL_CP(Vp + (size_t)vrow * N_ + t * 128 + vscol),
                LDS_CP(&Vs[ii * 512 + lane * 8]), 16, 0, 0);
        }
        __syncthreads();   // B: staging visible (compiler drains vmcnt)

        float ssum = 0.f;
#pragma unroll
        for (int kbk = 0; kbk < 4; kbk++) {      // 32-key blocks
            // S^T = K Q^T : D[key][q], key-rows kbk*32..+31
            f32x16 e;
#pragma unroll
            for (int r = 0; r < 16; r++) e[r] = 0.f;
#pragma unroll
            for (int ks = 0; ks < 4; ks++) {
                const int R  = kbk * 32 + l31;
                const int ch = ks * 2 + hh;               // 16B chunk index
                bf16x8 ak = *(const bf16x8*)(&Ks[R * 64 + ((ch ^ (R & 7)) << 3)]);
                e = __builtin_amdgcn_mfma_f32_32x32x16_bf16(ak, qf[ks], e, 0, 0, 0);
            }

            // softmax exponentials (Q pre-scaled by CEXP -> plain exp2)
#pragma unroll
            for (int r = 0; r < 16; r++) {
                e[r] = exp2f(e[r]);
                ssum += e[r];
            }

            // half-wave exchange: build P A-frags (keys kw*16 + hh*8 + j)
            float t1[4], t2[4];
#pragma unroll
            for (int j = 0; j < 4; j++) {
                const float s1 = hh ? e[j]     : e[4 + j];
                const float s2 = hh ? e[8 + j] : e[12 + j];
                t1[j] = __shfl_xor(s1, 32);
                t2[j] = __shfl_xor(s2, 32);
            }
            bf16x8 p0, p1;
#pragma unroll
            for (int j = 0; j < 4; j++) {
                p0[j]     = (bf16)(hh ? t1[j]      : e[j]);
                p0[4 + j] = (bf16)(hh ? e[4 + j]   : t1[j]);
                p1[j]     = (bf16)(hh ? t2[j]      : e[8 + j]);
                p1[4 + j] = (bf16)(hh ? e[12 + j]  : t2[j]);
            }

            // O += P V : D[q][d], B = V^T[d=l31][key]
#pragma unroll
            for (int dblk = 0; dblk < 2; dblk++) {
                const int R   = dblk * 32 + l31;
                const int ch0 = kbk * 4 + hh;
                const int ch1 = kbk * 4 + 2 + hh;
                bf16x8 bv0 = *(const bf16x8*)(&Vs[R * 128 + ((ch0 ^ (R & 15)) << 3)]);
                bf16x8 bv1 = *(const bf16x8*)(&Vs[R * 128 + ((ch1 ^ (R & 15)) << 3)]);
                oacc[dblk] = __builtin_amdgcn_mfma_f32_32x32x16_bf16(p0, bv0, oacc[dblk], 0, 0, 0);
                oacc[dblk] = __builtin_amdgcn_mfma_f32_32x32x16_bf16(p1, bv1, oacc[dblk], 0, 0, 0);
            }
        }
        ssum += __shfl_xor(ssum, 32);   // combine key-halves (same q = l31)
        lrow += ssum;
    }

    // epilogue: O row q=(r&3)+8*(r>>2)+4*hh, col d=dblk*32+l31
    const int head = bh & 15;
    const int b    = bh >> 4;
    const float linv = 1.0f / lrow;     // valid at lane with l31 == q
#pragma unroll
    for (int r = 0; r < 16; r++) {
        const int qr  = (r & 3) + 8 * (r >> 2) + 4 * hh;
        const float inv = __shfl(linv, qr);     // lane qr holds q=qr
        const int qrow = qt * 128 + wave * 32 + qr;
#pragma unroll
        for (int dblk = 0; dblk < 2; dblk++)
            ao[((size_t)(b * 2048 + qrow)) * 1024 + head * 64 + dblk * 32 + l31] =
                (bf16)(oacc[dblk][r] * inv);
    }
}

// ---------------------------------------------------------------------------
extern "C" void kernel_launch(void* const* d_in, const int* in_sizes, int n_in,
                              void* d_out, int out_size, void* d_ws, size_t ws_size,
                              hipStream_t stream)
{
    const float* x     = (const float*)d_in[0];   // [8192 x 1024] fp32
    const float* wqkv  = (const float*)d_in[1];   // [3072 x 1024] fp32
    const float* wproj = (const float*)d_in[2];   // [1024 x 1024] fp32
    float* out = (float*)d_out;                   // [8192 x 1024] fp32

    const size_t nx  = (size_t)M_ * DIM_;
    const size_t nwq = (size_t)3 * DIM_ * DIM_;
    const size_t nwp = (size_t)DIM_ * DIM_;
    const size_t seg = (size_t)B_ * H_ * N_ * DH_;

    bf16* xb     = (bf16*)d_ws;        // dead after QKV gemm; ao overlays it
    bf16* wqkvb  = xb + nx;            // contiguous with xb (cvt_all dest)
    bf16* wprojb = wqkvb + nwq;
    bf16* qb     = wprojb + nwp;
    bf16* kb     = qb + seg;
    bf16* vbT    = kb + seg;           // [bh][d][n]
    bf16* ao     = xb;

    const int nx4  = (int)(nx / 4), nwq4 = (int)(nwq / 4), nwp4 = (int)(nwp / 4);
    cvt_all<<<(nx4 + nwq4 + nwp4) / 256, 256, 0, stream>>>(
        x, wqkv, wproj, xb, nx4, nwq4, nwp4);

    gemm_bt<<<dim3(24, 64), 256, 0, stream>>>(xb, wqkvb, 3 * DIM_, DIM_, 1,
                                              nullptr, qb, kb, vbT);
    attn_kernel<<<dim3(1024), 256, 0, stream>>>(qb, kb, vbT, ao);
    gemm_bt<<<dim3(8, 64), 256, 0, stream>>>(ao, wprojb, DIM_, DIM_, 0,
                                             out, nullptr, nullptr, nullptr);
}

// Round 13
// 305.099 us; speedup vs baseline: 1.2750x; 1.0215x over previous
//
#include <hip/hip_runtime.h>

typedef __bf16 bf16;
typedef bf16 bf16x8 __attribute__((ext_vector_type(8)));
typedef float f32x4 __attribute__((ext_vector_type(4)));
typedef float f32x16 __attribute__((ext_vector_type(16)));

#define B_   4
#define N_   2048
#define DIM_ 1024
#define H_   16
#define DH_  64
#define M_   (B_ * N_)   // 8192

// log2(e) * (1/sqrt(64))
#define CEXP 0.18033688f

#define GLOBAL_CP(g) (const __attribute__((address_space(1))) void*)(g)
#define LDS_CP(l)    (__attribute__((address_space(3))) void*)(l)

// ---------------------------------------------------------------------------
// fused fp32 -> bf16 conversion for x | wqkv | wproj (contiguous dest in ws).
// ---------------------------------------------------------------------------
__global__ __launch_bounds__(256) void cvt_all(
    const float* __restrict__ x, const float* __restrict__ wq,
    const float* __restrict__ wp, bf16* __restrict__ o,
    int nx4, int nwq4, int nwp4)
{
    const int i = blockIdx.x * blockDim.x + threadIdx.x;
    const float* src; int si;
    if (i < nx4)                { src = x;  si = i; }
    else if (i < nx4 + nwq4)    { src = wq; si = i - nx4; }
    else                        { src = wp; si = i - nx4 - nwq4; }
    const float4 v = ((const float4*)src)[si];
    union { bf16 h[4]; uint2 u; } r;
    r.h[0] = (bf16)v.x; r.h[1] = (bf16)v.y;
    r.h[2] = (bf16)v.z; r.h[3] = (bf16)v.w;
    ((uint2*)o)[i] = r.u;
}

// ---------------------------------------------------------------------------
// GEMM: C[M x N] = A[M x K] @ B[N x K]^T   (bf16 in, fp32 acc)
// BK=64 (2 barriers per 64 K-elems -> half the drain count of BK=32).
// DMA staging (global_load_lds width 16), XOR source-swizzled chunks:
// LDS row-major [row][64]; slot s of row R holds global chunk s^(R&7).
// mode 0: fp32 C row-major; mode 1: scatter q/k [bh][n][d] (Q pre-scaled) +
// V transposed [bh][d][n].
// ---------------------------------------------------------------------------
__global__ __launch_bounds__(256) void gemm_bt(
    const bf16* __restrict__ A, const bf16* __restrict__ Bm,
    int Ndim, int K, int mode,
    float* __restrict__ outf,
    bf16* __restrict__ qb, bf16* __restrict__ kbv, bf16* __restrict__ vbT)
{
    __shared__ bf16 As[128 * 64];   // 16384 B
    __shared__ bf16 Bs[128 * 64];   // 16384 B

    const int tid  = threadIdx.x;
    const int wave = tid >> 6;
    const int lane = tid & 63;
    const int quad = lane >> 4;
    const int lr   = lane & 15;
    const int wr   = wave >> 1, wc = wave & 1;
    const int m0 = blockIdx.y * 128;
    const int n0 = blockIdx.x * 128;

    f32x4 acc[4][4];
#pragma unroll
    for (int i = 0; i < 4; i++)
#pragma unroll
        for (int j = 0; j < 4; j++) acc[i][j] = f32x4{0.f, 0.f, 0.f, 0.f};

    // staging map: issue ii covers rows ii*8..+7; lane -> row ii*8+(lane>>3),
    // source chunk ((lane&7)^((lane>>3)&7))*8; dest lane-linear.
    const int sl8 = lane >> 3;
    const int sc8 = ((lane & 7) ^ (sl8 & 7)) * 8;

    for (int k0 = 0; k0 < K; k0 += 64) {
        __syncthreads();  // prev-iter frag reads done
#pragma unroll
        for (int c = 0; c < 4; c++) {
            const int ii  = wave * 4 + c;
            const int row = ii * 8 + sl8;
            __builtin_amdgcn_global_load_lds(
                GLOBAL_CP(A + (size_t)(m0 + row) * K + k0 + sc8),
                LDS_CP(&As[ii * 512 + lane * 8]), 16, 0, 0);
            __builtin_amdgcn_global_load_lds(
                GLOBAL_CP(Bm + (size_t)(n0 + row) * K + k0 + sc8),
                LDS_CP(&Bs[ii * 512 + lane * 8]), 16, 0, 0);
        }
        __syncthreads();  // staging visible (vmcnt drain)

#pragma unroll
        for (int s = 0; s < 2; s++) {
            bf16x8 af[4], bfr[4];
#pragma unroll
            for (int i = 0; i < 4; i++) {
                const int R = wr * 64 + i * 16 + lr;
                af[i] = *(const bf16x8*)(&As[R * 64 + (((s * 4 + quad) ^ (R & 7)) << 3)]);
            }
#pragma unroll
            for (int j = 0; j < 4; j++) {
                const int R = wc * 64 + j * 16 + lr;
                bfr[j] = *(const bf16x8*)(&Bs[R * 64 + (((s * 4 + quad) ^ (R & 7)) << 3)]);
            }
#pragma unroll
            for (int i = 0; i < 4; i++)
#pragma unroll
                for (int j = 0; j < 4; j++)
                    acc[i][j] = __builtin_amdgcn_mfma_f32_16x16x32_bf16(
                        af[i], bfr[j], acc[i][j], 0, 0, 0);
        }
    }

#pragma unroll
    for (int i = 0; i < 4; i++) {
        const int mbase = m0 + wr * 64 + i * 16 + quad * 4;
#pragma unroll
        for (int j = 0; j < 4; j++) {
            const int n = n0 + wc * 64 + j * 16 + lr;
            if (mode == 0) {
#pragma unroll
                for (int r = 0; r < 4; r++)
                    outf[(size_t)(mbase + r) * Ndim + n] = acc[i][j][r];
            } else {
                const int which = n >> 10;
                const int h = (n >> 6) & 15;
                const int d = n & 63;
                const int b  = mbase >> 11;
                const int t0 = mbase & 2047;
                if (which == 2) {
                    union { uint2 u; bf16 hh[4]; } p;
#pragma unroll
                    for (int r = 0; r < 4; r++) p.hh[r] = (bf16)acc[i][j][r];
                    *(uint2*)(&vbT[(((size_t)(b * 16 + h)) * 64 + d) * 2048 + t0]) = p.u;
                } else {
                    bf16* dst = (which == 0) ? qb : kbv;
                    const float sc = (which == 0) ? CEXP : 1.0f;
#pragma unroll
                    for (int r = 0; r < 4; r++)
                        dst[(((size_t)(b * 16 + h)) * 2048 + t0 + r) * 64 + d] =
                            (bf16)(acc[i][j][r] * sc);
                }
            }
        }
    }
}

// ---------------------------------------------------------------------------
// Flash attention v10: v9 (32x32x16 MFMA + DMA staging) with the softmax
// row-sum moved onto the MFMA pipe: lacc = mfma(P, ones) accumulates
// l[q] = sum_k P[q][k] (all D-columns identical), replacing 128 VALU adds +
// 2 shuffles per iter and the epilogue shuffle (lacc shares oacc's C-layout
// row mapping, so inv = 1/lacc[r] is in-lane). Attn was VALU-bound (R12:
// VALUBusy 65% vs MfmaUtil 23%) — this shifts work to the idle pipe.
// ---------------------------------------------------------------------------
__global__ __launch_bounds__(256, 3) void attn_kernel(
    const bf16* __restrict__ qb, const bf16* __restrict__ kb,
    const bf16* __restrict__ vbT, bf16* __restrict__ ao)
{
    __shared__ bf16 Ks[128 * 64];   // 16384 B  [key][d], chunk-swizzled
    __shared__ bf16 Vs[64 * 128];   // 16384 B  [d][key], chunk-swizzled

    const int tid  = threadIdx.x;
    const int wave = tid >> 6;
    const int lane = tid & 63;
    const int l31  = lane & 31;
    const int hh   = lane >> 5;       // half-wave index

    // XCD swizzle: one head's 16 q-tiles on one XCD
    const int bid = blockIdx.x;
    const int qt  = (bid >> 3) & 15;
    const int bh  = ((bid >> 7) << 3) | (bid & 7);

    const bf16* Q  = qb  + (size_t)bh * N_ * DH_;
    const bf16* Kp = kb  + (size_t)bh * N_ * DH_;
    const bf16* Vp = vbT + (size_t)bh * DH_ * N_;   // [d][n]

    // Q B-frags: B[q=l31][d = ks*16 + hh*8 + j], loaded once from global
    bf16x8 qf[4];
#pragma unroll
    for (int ks = 0; ks < 4; ks++)
        qf[ks] = *(const bf16x8*)(Q + (size_t)(qt * 128 + wave * 32 + l31) * DH_
                                    + ks * 16 + hh * 8);

    bf16x8 onesf;
#pragma unroll
    for (int j = 0; j < 8; j++) onesf[j] = (bf16)1.0f;

    const int krow0 = (lane >> 3);
    const int kscol = ((lane & 7) ^ ((lane >> 3) & 7)) * 8;
    const int vrow0 = (lane >> 4);

    f32x16 oacc[2], lacc;
#pragma unroll
    for (int d = 0; d < 2; d++)
#pragma unroll
        for (int r = 0; r < 16; r++) oacc[d][r] = 0.f;
#pragma unroll
    for (int r = 0; r < 16; r++) lacc[r] = 0.f;

    for (int t = 0; t < N_ / 128; t++) {
        __syncthreads();   // A: prev-iter Ks/Vs readers done
        // DMA-stage K tile (16 KB) and V tile (16 KB)
#pragma unroll
        for (int c = 0; c < 4; c++) {
            const int ii = wave * 4 + c;
            const int krow = ii * 8 + krow0;
            __builtin_amdgcn_global_load_lds(
                GLOBAL_CP(Kp + (size_t)(t * 128 + krow) * DH_ + kscol),
                LDS_CP(&Ks[ii * 512 + lane * 8]), 16, 0, 0);
            const int vrow = ii * 4 + vrow0;
            const int vscol = ((lane & 15) ^ (vrow & 15)) * 8;
            __builtin_amdgcn_global_load_lds(
                GLOBAL_CP(Vp + (size_t)vrow * N_ + t * 128 + vscol),
                LDS_CP(&Vs[ii * 512 + lane * 8]), 16, 0, 0);
        }
        __syncthreads();   // B: staging visible (compiler drains vmcnt)

#pragma unroll
        for (int kbk = 0; kbk < 4; kbk++) {      // 32-key blocks
            // S^T = K Q^T : D[key][q], key-rows kbk*32..+31
            f32x16 e;
#pragma unroll
            for (int r = 0; r < 16; r++) e[r] = 0.f;
#pragma unroll
            for (int ks = 0; ks < 4; ks++) {
                const int R  = kbk * 32 + l31;
                const int ch = ks * 2 + hh;               // 16B chunk index
                bf16x8 ak = *(const bf16x8*)(&Ks[R * 64 + ((ch ^ (R & 7)) << 3)]);
                e = __builtin_amdgcn_mfma_f32_32x32x16_bf16(ak, qf[ks], e, 0, 0, 0);
            }

            // softmax exponentials (Q pre-scaled by CEXP -> plain exp2)
#pragma unroll
            for (int r = 0; r < 16; r++)
                e[r] = exp2f(e[r]);

            // half-wave exchange: build P A-frags (keys kw*16 + hh*8 + j)
            float t1[4], t2[4];
#pragma unroll
            for (int j = 0; j < 4; j++) {
                const float s1 = hh ? e[j]     : e[4 + j];
                const float s2 = hh ? e[8 + j] : e[12 + j];
                t1[j] = __shfl_xor(s1, 32);
                t2[j] = __shfl_xor(s2, 32);
            }
            bf16x8 p0, p1;
#pragma unroll
            for (int j = 0; j < 4; j++) {
                p0[j]     = (bf16)(hh ? t1[j]      : e[j]);
                p0[4 + j] = (bf16)(hh ? e[4 + j]   : t1[j]);
                p1[j]     = (bf16)(hh ? t2[j]      : e[8 + j]);
                p1[4 + j] = (bf16)(hh ? e[12 + j]  : t2[j]);
            }

            // l[q] += sum_k P : MFMA with B = ones (all D-columns identical)
            lacc = __builtin_amdgcn_mfma_f32_32x32x16_bf16(p0, onesf, lacc, 0, 0, 0);
            lacc = __builtin_amdgcn_mfma_f32_32x32x16_bf16(p1, onesf, lacc, 0, 0, 0);

            // O += P V : D[q][d], B = V^T[d=l31][key]
#pragma unroll
            for (int dblk = 0; dblk < 2; dblk++) {
                const int R   = dblk * 32 + l31;
                const int ch0 = kbk * 4 + hh;
                const int ch1 = kbk * 4 + 2 + hh;
                bf16x8 bv0 = *(const bf16x8*)(&Vs[R * 128 + ((ch0 ^ (R & 15)) << 3)]);
                bf16x8 bv1 = *(const bf16x8*)(&Vs[R * 128 + ((ch1 ^ (R & 15)) << 3)]);
                oacc[dblk] = __builtin_amdgcn_mfma_f32_32x32x16_bf16(p0, bv0, oacc[dblk], 0, 0, 0);
                oacc[dblk] = __builtin_amdgcn_mfma_f32_32x32x16_bf16(p1, bv1, oacc[dblk], 0, 0, 0);
            }
        }
    }

    // epilogue: O row q=(r&3)+8*(r>>2)+4*hh, col d=dblk*32+l31.
    // lacc shares the same row mapping -> 1/lacc[r] is the right l, in-lane.
    const int head = bh & 15;
    const int b    = bh >> 4;
#pragma unroll
    for (int r = 0; r < 16; r++) {
        const int qr  = (r & 3) + 8 * (r >> 2) + 4 * hh;
        const float inv = 1.0f / lacc[r];
        const int qrow = qt * 128 + wave * 32 + qr;
#pragma unroll
        for (int dblk = 0; dblk < 2; dblk++)
            ao[((size_t)(b * 2048 + qrow)) * 1024 + head * 64 + dblk * 32 + l31] =
                (bf16)(oacc[dblk][r] * inv);
    }
}

// ---------------------------------------------------------------------------
extern "C" void kernel_launch(void* const* d_in, const int* in_sizes, int n_in,
                              void* d_out, int out_size, void* d_ws, size_t ws_size,
                              hipStream_t stream)
{
    const float* x     = (const float*)d_in[0];   // [8192 x 1024] fp32
    const float* wqkv  = (const float*)d_in[1];   // [3072 x 1024] fp32
    const float* wproj = (const float*)d_in[2];   // [1024 x 1024] fp32
    float* out = (float*)d_out;                   // [8192 x 1024] fp32

    const size_t nx  = (size_t)M_ * DIM_;
    const size_t nwq = (size_t)3 * DIM_ * DIM_;
    const size_t nwp = (size_t)DIM_ * DIM_;
    const size_t seg = (size_t)B_ * H_ * N_ * DH_;

    bf16* xb     = (bf16*)d_ws;        // dead after QKV gemm; ao overlays it
    bf16* wqkvb  = xb + nx;            // contiguous with xb (cvt_all dest)
    bf16* wprojb = wqkvb + nwq;
    bf16* qb     = wprojb + nwp;
    bf16* kb     = qb + seg;
    bf16* vbT    = kb + seg;           // [bh][d][n]
    bf16* ao     = xb;

    const int nx4  = (int)(nx / 4), nwq4 = (int)(nwq / 4), nwp4 = (int)(nwp / 4);
    cvt_all<<<(nx4 + nwq4 + nwp4) / 256, 256, 0, stream>>>(
        x, wqkv, wproj, xb, nx4, nwq4, nwp4);

    gemm_bt<<<dim3(24, 64), 256, 0, stream>>>(xb, wqkvb, 3 * DIM_, DIM_, 1,
                                              nullptr, qb, kb, vbT);
    attn_kernel<<<dim3(1024), 256, 0, stream>>>(qb, kb, vbT, ao);
    gemm_bt<<<dim3(8, 64), 256, 0, stream>>>(ao, wprojb, DIM_, DIM_, 0,
                                             out, nullptr, nullptr, nullptr);
}

// Round 14
// 299.107 us; speedup vs baseline: 1.3005x; 1.0200x over previous
//
#include <hip/hip_runtime.h>

typedef __bf16 bf16;
typedef bf16 bf16x8 __attribute__((ext_vector_type(8)));
typedef float f32x4 __attribute__((ext_vector_type(4)));
typedef float f32x16 __attribute__((ext_vector_type(16)));

#define B_   4
#define N_   2048
#define DIM_ 1024
#define H_   16
#define DH_  64
#define M_   (B_ * N_)   // 8192

// log2(e) * (1/sqrt(64))
#define CEXP 0.18033688f

#define GLOBAL_CP(g) (const __attribute__((address_space(1))) void*)(g)
#define LDS_CP(l)    (__attribute__((address_space(3))) void*)(l)

// ---------------------------------------------------------------------------
// fused fp32 -> bf16 conversion for x | wqkv | wproj (contiguous dest in ws).
// ---------------------------------------------------------------------------
__global__ __launch_bounds__(256) void cvt_all(
    const float* __restrict__ x, const float* __restrict__ wq,
    const float* __restrict__ wp, bf16* __restrict__ o,
    int nx4, int nwq4, int nwp4)
{
    const int i = blockIdx.x * blockDim.x + threadIdx.x;
    const float* src; int si;
    if (i < nx4)                { src = x;  si = i; }
    else if (i < nx4 + nwq4)    { src = wq; si = i - nx4; }
    else                        { src = wp; si = i - nx4 - nwq4; }
    const float4 v = ((const float4*)src)[si];
    union { bf16 h[4]; uint2 u; } r;
    r.h[0] = (bf16)v.x; r.h[1] = (bf16)v.y;
    r.h[2] = (bf16)v.z; r.h[3] = (bf16)v.w;
    ((uint2*)o)[i] = r.u;
}

// ---------------------------------------------------------------------------
// GEMM (unchanged from R13): BK=64, DMA staging, XOR source-swizzled chunks.
// mode 0: fp32 C row-major; mode 1: scatter q/k [bh][n][d] (Q pre-scaled) +
// V transposed [bh][d][n].
// ---------------------------------------------------------------------------
__global__ __launch_bounds__(256) void gemm_bt(
    const bf16* __restrict__ A, const bf16* __restrict__ Bm,
    int Ndim, int K, int mode,
    float* __restrict__ outf,
    bf16* __restrict__ qb, bf16* __restrict__ kbv, bf16* __restrict__ vbT)
{
    __shared__ bf16 As[128 * 64];   // 16384 B
    __shared__ bf16 Bs[128 * 64];   // 16384 B

    const int tid  = threadIdx.x;
    const int wave = tid >> 6;
    const int lane = tid & 63;
    const int quad = lane >> 4;
    const int lr   = lane & 15;
    const int wr   = wave >> 1, wc = wave & 1;
    const int m0 = blockIdx.y * 128;
    const int n0 = blockIdx.x * 128;

    f32x4 acc[4][4];
#pragma unroll
    for (int i = 0; i < 4; i++)
#pragma unroll
        for (int j = 0; j < 4; j++) acc[i][j] = f32x4{0.f, 0.f, 0.f, 0.f};

    const int sl8 = lane >> 3;
    const int sc8 = ((lane & 7) ^ (sl8 & 7)) * 8;

    for (int k0 = 0; k0 < K; k0 += 64) {
        __syncthreads();  // prev-iter frag reads done
#pragma unroll
        for (int c = 0; c < 4; c++) {
            const int ii  = wave * 4 + c;
            const int row = ii * 8 + sl8;
            __builtin_amdgcn_global_load_lds(
                GLOBAL_CP(A + (size_t)(m0 + row) * K + k0 + sc8),
                LDS_CP(&As[ii * 512 + lane * 8]), 16, 0, 0);
            __builtin_amdgcn_global_load_lds(
                GLOBAL_CP(Bm + (size_t)(n0 + row) * K + k0 + sc8),
                LDS_CP(&Bs[ii * 512 + lane * 8]), 16, 0, 0);
        }
        __syncthreads();  // staging visible (vmcnt drain)

#pragma unroll
        for (int s = 0; s < 2; s++) {
            bf16x8 af[4], bfr[4];
#pragma unroll
            for (int i = 0; i < 4; i++) {
                const int R = wr * 64 + i * 16 + lr;
                af[i] = *(const bf16x8*)(&As[R * 64 + (((s * 4 + quad) ^ (R & 7)) << 3)]);
            }
#pragma unroll
            for (int j = 0; j < 4; j++) {
                const int R = wc * 64 + j * 16 + lr;
                bfr[j] = *(const bf16x8*)(&Bs[R * 64 + (((s * 4 + quad) ^ (R & 7)) << 3)]);
            }
#pragma unroll
            for (int i = 0; i < 4; i++)
#pragma unroll
                for (int j = 0; j < 4; j++)
                    acc[i][j] = __builtin_amdgcn_mfma_f32_16x16x32_bf16(
                        af[i], bfr[j], acc[i][j], 0, 0, 0);
        }
    }

#pragma unroll
    for (int i = 0; i < 4; i++) {
        const int mbase = m0 + wr * 64 + i * 16 + quad * 4;
#pragma unroll
        for (int j = 0; j < 4; j++) {
            const int n = n0 + wc * 64 + j * 16 + lr;
            if (mode == 0) {
#pragma unroll
                for (int r = 0; r < 4; r++)
                    outf[(size_t)(mbase + r) * Ndim + n] = acc[i][j][r];
            } else {
                const int which = n >> 10;
                const int h = (n >> 6) & 15;
                const int d = n & 63;
                const int b  = mbase >> 11;
                const int t0 = mbase & 2047;
                if (which == 2) {
                    union { uint2 u; bf16 hh[4]; } p;
#pragma unroll
                    for (int r = 0; r < 4; r++) p.hh[r] = (bf16)acc[i][j][r];
                    *(uint2*)(&vbT[(((size_t)(b * 16 + h)) * 64 + d) * 2048 + t0]) = p.u;
                } else {
                    bf16* dst = (which == 0) ? qb : kbv;
                    const float sc = (which == 0) ? CEXP : 1.0f;
#pragma unroll
                    for (int r = 0; r < 4; r++)
                        dst[(((size_t)(b * 16 + h)) * 2048 + t0 + r) * 64 + d] =
                            (bf16)(acc[i][j][r] * sc);
                }
            }
        }
    }
}

// ---------------------------------------------------------------------------
// Flash attention v11: R12 structure (VALU row-sum — measured best) with a
// packed-dword half-wave exchange: P converted to bf16 first, C/D-adjacent
// pairs packed into dwords g[m]=pack(e[2m],e[2m+1]) (exactly the PV A-frag
// dword pairs), per-hh pre-select -> only 4 dword shuffles per 32-key block
// (was 8 float shuffles) and half the result selects.
// ---------------------------------------------------------------------------
__global__ __launch_bounds__(256, 3) void attn_kernel(
    const bf16* __restrict__ qb, const bf16* __restrict__ kb,
    const bf16* __restrict__ vbT, bf16* __restrict__ ao)
{
    __shared__ bf16 Ks[128 * 64];   // 16384 B  [key][d], chunk-swizzled
    __shared__ bf16 Vs[64 * 128];   // 16384 B  [d][key], chunk-swizzled

    const int tid  = threadIdx.x;
    const int wave = tid >> 6;
    const int lane = tid & 63;
    const int l31  = lane & 31;
    const int hh   = lane >> 5;       // half-wave index

    // XCD swizzle: one head's 16 q-tiles on one XCD
    const int bid = blockIdx.x;
    const int qt  = (bid >> 3) & 15;
    const int bh  = ((bid >> 7) << 3) | (bid & 7);

    const bf16* Q  = qb  + (size_t)bh * N_ * DH_;
    const bf16* Kp = kb  + (size_t)bh * N_ * DH_;
    const bf16* Vp = vbT + (size_t)bh * DH_ * N_;   // [d][n]

    // Q B-frags: B[q=l31][d = ks*16 + hh*8 + j], loaded once from global
    bf16x8 qf[4];
#pragma unroll
    for (int ks = 0; ks < 4; ks++)
        qf[ks] = *(const bf16x8*)(Q + (size_t)(qt * 128 + wave * 32 + l31) * DH_
                                    + ks * 16 + hh * 8);

    const int krow0 = (lane >> 3);
    const int kscol = ((lane & 7) ^ ((lane >> 3) & 7)) * 8;
    const int vrow0 = (lane >> 4);

    float lrow = 0.f;
    f32x16 oacc[2];
#pragma unroll
    for (int d = 0; d < 2; d++)
#pragma unroll
        for (int r = 0; r < 16; r++) oacc[d][r] = 0.f;

    for (int t = 0; t < N_ / 128; t++) {
        __syncthreads();   // A: prev-iter Ks/Vs readers done
        // DMA-stage K tile (16 KB) and V tile (16 KB)
#pragma unroll
        for (int c = 0; c < 4; c++) {
            const int ii = wave * 4 + c;
            const int krow = ii * 8 + krow0;
            __builtin_amdgcn_global_load_lds(
                GLOBAL_CP(Kp + (size_t)(t * 128 + krow) * DH_ + kscol),
                LDS_CP(&Ks[ii * 512 + lane * 8]), 16, 0, 0);
            const int vrow = ii * 4 + vrow0;
            const int vscol = ((lane & 15) ^ (vrow & 15)) * 8;
            __builtin_amdgcn_global_load_lds(
                GLOBAL_CP(Vp + (size_t)vrow * N_ + t * 128 + vscol),
                LDS_CP(&Vs[ii * 512 + lane * 8]), 16, 0, 0);
        }
        __syncthreads();   // B: staging visible (compiler drains vmcnt)

        float ssum = 0.f;
#pragma unroll
        for (int kbk = 0; kbk < 4; kbk++) {      // 32-key blocks
            // S^T = K Q^T : D[key][q], key-rows kbk*32..+31
            f32x16 e;
#pragma unroll
            for (int r = 0; r < 16; r++) e[r] = 0.f;
#pragma unroll
            for (int ks = 0; ks < 4; ks++) {
                const int R  = kbk * 32 + l31;
                const int ch = ks * 2 + hh;               // 16B chunk index
                bf16x8 ak = *(const bf16x8*)(&Ks[R * 64 + ((ch ^ (R & 7)) << 3)]);
                e = __builtin_amdgcn_mfma_f32_32x32x16_bf16(ak, qf[ks], e, 0, 0, 0);
            }

            // softmax exponentials + fp32 row-sum contribution
#pragma unroll
            for (int r = 0; r < 16; r++) {
                e[r] = exp2f(e[r]);
                ssum += e[r];
            }

            // pack C/D-adjacent pairs into bf16x2 dwords (A-frag dword pairs):
            // g[m] covers keys base(m)+4*hh+{0,1}, base = (m&1)*2 + (m>>1)*8
            uint g[8];
#pragma unroll
            for (int m = 0; m < 8; m++) {
                union { uint u; bf16 h2[2]; } pk;
                pk.h2[0] = (bf16)e[2 * m];
                pk.h2[1] = (bf16)e[2 * m + 1];
                g[m] = pk.u;
            }

            // 4 dword shuffles with per-hh pre-select:
            // p0 (keys 0..15):  hh=0 needs partner g0,g1; hh=1 needs partner g2,g3
            const uint r0 = (uint)__shfl_xor((int)(hh ? g[0] : g[2]), 32);
            const uint r1 = (uint)__shfl_xor((int)(hh ? g[1] : g[3]), 32);
            // p1 (keys 16..31): hh=0 needs partner g4,g5; hh=1 needs partner g6,g7
            const uint r2 = (uint)__shfl_xor((int)(hh ? g[4] : g[6]), 32);
            const uint r3 = (uint)__shfl_xor((int)(hh ? g[5] : g[7]), 32);

            union { uint u[4]; bf16x8 v; } p0u, p1u;
            p0u.u[0] = hh ? r0   : g[0];
            p0u.u[1] = hh ? r1   : g[1];
            p0u.u[2] = hh ? g[2] : r0;
            p0u.u[3] = hh ? g[3] : r1;
            p1u.u[0] = hh ? r2   : g[4];
            p1u.u[1] = hh ? r3   : g[5];
            p1u.u[2] = hh ? g[6] : r2;
            p1u.u[3] = hh ? g[7] : r3;

            // O += P V : D[q][d], B = V^T[d=l31][key]
#pragma unroll
            for (int dblk = 0; dblk < 2; dblk++) {
                const int R   = dblk * 32 + l31;
                const int ch0 = kbk * 4 + hh;
                const int ch1 = kbk * 4 + 2 + hh;
                bf16x8 bv0 = *(const bf16x8*)(&Vs[R * 128 + ((ch0 ^ (R & 15)) << 3)]);
                bf16x8 bv1 = *(const bf16x8*)(&Vs[R * 128 + ((ch1 ^ (R & 15)) << 3)]);
                oacc[dblk] = __builtin_amdgcn_mfma_f32_32x32x16_bf16(p0u.v, bv0, oacc[dblk], 0, 0, 0);
                oacc[dblk] = __builtin_amdgcn_mfma_f32_32x32x16_bf16(p1u.v, bv1, oacc[dblk], 0, 0, 0);
            }
        }
        ssum += __shfl_xor(ssum, 32);   // combine key-halves (same q = l31)
        lrow += ssum;
    }

    // epilogue: O row q=(r&3)+8*(r>>2)+4*hh, col d=dblk*32+l31
    const int head = bh & 15;
    const int b    = bh >> 4;
    const float linv = 1.0f / lrow;     // valid at lane with l31 == q
#pragma unroll
    for (int r = 0; r < 16; r++) {
        const int qr  = (r & 3) + 8 * (r >> 2) + 4 * hh;
        const float inv = __shfl(linv, qr);     // lane qr holds q=qr
        const int qrow = qt * 128 + wave * 32 + qr;
#pragma unroll
        for (int dblk = 0; dblk < 2; dblk++)
            ao[((size_t)(b * 2048 + qrow)) * 1024 + head * 64 + dblk * 32 + l31] =
                (bf16)(oacc[dblk][r] * inv);
    }
}

// ---------------------------------------------------------------------------
extern "C" void kernel_launch(void* const* d_in, const int* in_sizes, int n_in,
                              void* d_out, int out_size, void* d_ws, size_t ws_size,
                              hipStream_t stream)
{
    const float* x     = (const float*)d_in[0];   // [8192 x 1024] fp32
    const float* wqkv  = (const float*)d_in[1];   // [3072 x 1024] fp32
    const float* wproj = (const float*)d_in[2];   // [1024 x 1024] fp32
    float* out = (float*)d_out;                   // [8192 x 1024] fp32

    const size_t nx  = (size_t)M_ * DIM_;
    const size_t nwq = (size_t)3 * DIM_ * DIM_;
    const size_t nwp = (size_t)DIM_ * DIM_;
    const size_t seg = (size_t)B_ * H_ * N_ * DH_;

    bf16* xb     = (bf16*)d_ws;        // dead after QKV gemm; ao overlays it
    bf16* wqkvb  = xb + nx;            // contiguous with xb (cvt_all dest)
    bf16* wprojb = wqkvb + nwq;
    bf16* qb     = wprojb + nwp;
    bf16* kb     = qb + seg;
    bf16* vbT    = kb + seg;           // [bh][d][n]
    bf16* ao     = xb;

    const int nx4  = (int)(nx / 4), nwq4 = (int)(nwq / 4), nwp4 = (int)(nwp / 4);
    cvt_all<<<(nx4 + nwq4 + nwp4) / 256, 256, 0, stream>>>(
        x, wqkv, wproj, xb, nx4, nwq4, nwp4);

    gemm_bt<<<dim3(24, 64), 256, 0, stream>>>(xb, wqkvb, 3 * DIM_, DIM_, 1,
                                              nullptr, qb, kb, vbT);
    attn_kernel<<<dim3(1024), 256, 0, stream>>>(qb, kb, vbT, ao);
    gemm_bt<<<dim3(8, 64), 256, 0, stream>>>(ao, wprojb, DIM_, DIM_, 0,
                                             out, nullptr, nullptr, nullptr);
}